// Round 2
// baseline (146.560 us; speedup 1.0000x reference)
//
#include <hip/hip_runtime.h>

#define DD 128
#define BM 64          // rows per block (16 per wave)
#define T_TYPES 16

typedef __bf16 bf16x8 __attribute__((ext_vector_type(8)));
typedef float  f32x4  __attribute__((ext_vector_type(4)));

__device__ __forceinline__ unsigned short f2bf(float f) {
    union { float f; unsigned int u; } c; c.f = f;
    unsigned int u = c.u;
    u += 0x7fffu + ((u >> 16) & 1u);   // RTNE
    return (unsigned short)(u >> 16);
}

// ---------- Pre-kernel: W fp32 [t][k][n] -> bf16 [t][m=n][k] in d_ws ----------
// grid = 64 blocks: t = blk>>2, m0 = (blk&3)*32. LDS-tiled transpose, both
// sides coalesced. Runs every launch (re-poisoned ws), ~1 MB traffic.
__global__ __launch_bounds__(256) void transpose_w_kernel(
    const float* __restrict__ w, unsigned short* __restrict__ wbf)
{
    __shared__ float lds[DD * 33];            // [k][m-local 32 + 1 pad]
    const int t   = blockIdx.x >> 2;
    const int m0  = (blockIdx.x & 3) * 32;
    const int tid = threadIdx.x;
    const float* wt = w + (size_t)t * DD * DD;

    #pragma unroll
    for (int i = 0; i < 4; ++i) {             // 1024 float4 reads total
        int f = tid + i * 256;
        int k = f >> 3;                        // 8 float4 per k-row (32 floats)
        int c = (f & 7) * 4;                   // m-local
        float4 v = *(const float4*)&wt[k * DD + m0 + c];
        lds[k * 33 + c + 0] = v.x;
        lds[k * 33 + c + 1] = v.y;
        lds[k * 33 + c + 2] = v.z;
        lds[k * 33 + c + 3] = v.w;
    }
    __syncthreads();
    #pragma unroll
    for (int i = 0; i < 4; ++i) {             // 1024 ushort4 writes total
        int g  = tid + i * 256;
        int ml = g >> 5;                       // m-local 0..31
        int k4 = (g & 31) * 4;                 // k 0..124 step 4
        ushort4 o;
        o.x = f2bf(lds[(k4 + 0) * 33 + ml]);
        o.y = f2bf(lds[(k4 + 1) * 33 + ml]);
        o.z = f2bf(lds[(k4 + 2) * 33 + ml]);
        o.w = f2bf(lds[(k4 + 3) * 33 + ml]);
        *(ushort4*)&wbf[((size_t)t * DD + m0 + ml) * DD + k4] = o;
    }
}

// ---------- Main kernel: no LDS, no barriers ----------
// MFMA roles: A = W^T fragment (m = out-col), B = x fragment (n = x-row).
// D[m][n]: lane(q,n16) holds rows m=q*4+reg (out-cols, contiguous!) for
// x-row n16  ->  epilogue = 8 coalesced float4 stores per lane.
__global__ __launch_bounds__(256, 4) void hetero_main_kernel(
    const float* __restrict__ x,
    const int*   __restrict__ tv,
    const __bf16* __restrict__ wbf,   // [T][m][k] bf16
    const float* __restrict__ bias,   // [T][128]
    float*       __restrict__ out)    // [N][128]
{
    const int tid   = threadIdx.x;
    const int wave  = tid >> 6;
    const int lane  = tid & 63;
    const int q     = lane >> 4;
    const int n16   = lane & 15;
    const int wrow0 = blockIdx.x * BM + wave * 16;
    const int grow  = wrow0 + n16;           // this lane's x/out row

    const int t0 = tv[wrow0];
    const int t1 = tv[wrow0 + 15];

    // x fragments: B[k=q*8+j][n=n16] = x[grow][kk*32 + q*8 + j]; loaded once
    bf16x8 xb[4];
    {
        const float* xr = x + (size_t)grow * DD;
        #pragma unroll
        for (int kk = 0; kk < 4; ++kk) {
            float4 v0 = *(const float4*)&xr[kk * 32 + q * 8];
            float4 v1 = *(const float4*)&xr[kk * 32 + q * 8 + 4];
            bf16x8 b;
            b[0] = (__bf16)v0.x; b[1] = (__bf16)v0.y;
            b[2] = (__bf16)v0.z; b[3] = (__bf16)v0.w;
            b[4] = (__bf16)v1.x; b[5] = (__bf16)v1.y;
            b[6] = (__bf16)v1.z; b[7] = (__bf16)v1.w;
            xb[kk] = b;
        }
    }

    const int myt = (t0 == t1) ? t0 : tv[grow];

    for (int t = t0; t <= t1; ++t) {
        f32x4 acc[8];
        #pragma unroll
        for (int mt = 0; mt < 8; ++mt) acc[mt] = (f32x4){0.f, 0.f, 0.f, 0.f};

        const __bf16* wt = wbf + (size_t)t * DD * DD;
        #pragma unroll
        for (int kk = 0; kk < 4; ++kk) {
            #pragma unroll
            for (int mt = 0; mt < 8; ++mt) {
                // A[m=n16][k=q*8+j] of m-tile mt  ->  wbf[t][mt*16+n16][kk*32+q*8]
                bf16x8 a = *(const bf16x8*)&wt[(mt * 16 + n16) * DD + kk * 32 + q * 8];
                acc[mt] = __builtin_amdgcn_mfma_f32_16x16x32_bf16(a, xb[kk], acc[mt], 0, 0, 0);
            }
        }

        const bool st = (myt == t);
        float* orow = out + (size_t)grow * DD;
        #pragma unroll
        for (int mt = 0; mt < 8; ++mt) {
            float4 bv = *(const float4*)&bias[t * DD + mt * 16 + q * 4];
            if (st) {
                float4 r;
                r.x = acc[mt][0] + bv.x;
                r.y = acc[mt][1] + bv.y;
                r.z = acc[mt][2] + bv.z;
                r.w = acc[mt][3] + bv.w;
                *(float4*)&orow[mt * 16 + q * 4] = r;
            }
        }
    }
}

extern "C" void kernel_launch(void* const* d_in, const int* in_sizes, int n_in,
                              void* d_out, int out_size, void* d_ws, size_t ws_size,
                              hipStream_t stream) {
    const float* x    = (const float*)d_in[0];
    const int*   tv   = (const int*)d_in[1];
    const float* w    = (const float*)d_in[2];
    const float* bias = (const float*)d_in[3];
    float*       out  = (float*)d_out;
    unsigned short* wbf = (unsigned short*)d_ws;   // 16*128*128*2 = 512 KB

    int nrows = in_sizes[0] / DD;                  // 131072
    int grid  = nrows / BM;                        // 2048

    hipLaunchKernelGGL(transpose_w_kernel, dim3(T_TYPES * 4), dim3(256), 0, stream,
                       w, wbf);
    hipLaunchKernelGGL(hetero_main_kernel, dim3(grid), dim3(256), 0, stream,
                       x, tv, (const __bf16*)wbf, bias, out);
}

// Round 3
// 131.649 us; speedup vs baseline: 1.1133x; 1.1133x over previous
//
#include <hip/hip_runtime.h>

#define DD 128
#define BM 64
#define T_TYPES 16

typedef __bf16 bf16x8 __attribute__((ext_vector_type(8)));
typedef __bf16 bf16x4 __attribute__((ext_vector_type(4)));
typedef float  f32x4  __attribute__((ext_vector_type(4)));

// ---------- Pre-kernel: w fp32 [t][k][n] -> bf16 MFMA-fragment order ----------
// wbf layout: [t][nt(8)][kk(4)][lane(64)][j(8)] bf16, where the B-fragment for
// (nt,kk) held by lane(q=lane>>4, n16=lane&15) is B[k=kk*32+q*8+j][n=nt*16+n16]
// = w[t][k][n].  Main-kernel B loads become base + lane*16B : fully contiguous.
__global__ __launch_bounds__(256) void transpose_w_frag_kernel(
    const float* __restrict__ w, unsigned short* __restrict__ wbf)
{
    __shared__ float lds[DD * 33];            // [k][n-local 32 + pad]
    const int t   = blockIdx.x >> 2;
    const int n0  = (blockIdx.x & 3) * 32;
    const int tid = threadIdx.x;
    const float* wt = w + (size_t)t * DD * DD;

    #pragma unroll
    for (int i = 0; i < 4; ++i) {             // coalesced float4 reads
        int f = tid + i * 256;
        int k = f >> 3;                        // 8 float4 per k-row of 32 cols
        int c = (f & 7) * 4;
        float4 v = *(const float4*)&wt[k * DD + n0 + c];
        lds[k * 33 + c + 0] = v.x;
        lds[k * 33 + c + 1] = v.y;
        lds[k * 33 + c + 2] = v.z;
        lds[k * 33 + c + 3] = v.w;
    }
    __syncthreads();
    #pragma unroll
    for (int i = 0; i < 4; ++i) {
        int g  = tid + i * 256;
        int nl = g >> 5;                       // n-local 0..31
        int k4 = (g & 31) * 4;                 // k, step 4 (stays within one q)
        int n  = n0 + nl;
        int nt  = n >> 4, n16 = n & 15;
        int kk  = k4 >> 5, q = (k4 >> 3) & 3, jb = k4 & 7;   // jb in {0,4}
        int lane = q * 16 + n16;
        size_t ofs = ((((size_t)t * 8 + nt) * 4 + kk) * 64 + lane) * 8 + jb;
        ushort4 o;
        union { __bf16 b; unsigned short u; } cv;
        cv.b = (__bf16)lds[(k4 + 0) * 33 + nl]; o.x = cv.u;
        cv.b = (__bf16)lds[(k4 + 1) * 33 + nl]; o.y = cv.u;
        cv.b = (__bf16)lds[(k4 + 2) * 33 + nl]; o.z = cv.u;
        cv.b = (__bf16)lds[(k4 + 3) * 33 + nl]; o.w = cv.u;
        *(ushort4*)&wbf[ofs] = o;
    }
}

// ---------- Main kernel ----------
// A = x rows (16/wave, staged in swizzled bf16 LDS), B = W fragments straight
// from global in fragment order (contiguous per wave), D[row=q*4+reg][col=n16].
__global__ __launch_bounds__(256, 4) void hetero_main_kernel(
    const float* __restrict__ x,
    const int*   __restrict__ tv,
    const __bf16* __restrict__ wbf,   // fragment-ordered bf16 W
    const float* __restrict__ bias,   // [T][128]
    float*       __restrict__ out)    // [N][128]
{
    __shared__ __bf16 As[BM * DD];    // swizzled: addr(r,k)=r*128+((k>>3)^(r&7))*8+(k&7)

    const int tid  = threadIdx.x;
    const int wave = tid >> 6;
    const int lane = tid & 63;
    const int q    = lane >> 4;
    const int n16  = lane & 15;
    const int row0 = blockIdx.x * BM;

    const int t0 = tv[row0];
    const int t1 = tv[row0 + BM - 1];
    const bool uniform = (t0 == t1);

    // ---- Stage A: coalesced float4 reads -> bf16 -> swizzled LDS ----
    {
        const float4* xg = (const float4*)(x + (size_t)row0 * DD);
        #pragma unroll
        for (int i = 0; i < 8; ++i) {
            int f  = tid + i * 256;
            int r  = f >> 5;                 // 32 float4 per row
            int c4 = (f & 31) << 2;          // k base, step 4
            float4 v = xg[f];
            bf16x4 pk;
            pk[0] = (__bf16)v.x; pk[1] = (__bf16)v.y;
            pk[2] = (__bf16)v.z; pk[3] = (__bf16)v.w;
            int g = c4 >> 3;                 // 16B granule in row
            *(bf16x4*)&As[r * DD + ((g ^ (r & 7)) << 3) + (c4 & 7)] = pk;
        }
    }
    __syncthreads();

    // ---- A fragments: A[m=wave*16+n16][k=kk*32+q*8+j], swizzle-corrected ----
    bf16x8 a[4];
    {
        const __bf16* arow = &As[(wave * 16 + n16) * DD];
        #pragma unroll
        for (int kk = 0; kk < 4; ++kk) {
            int gr = ((kk << 2) | q) ^ (n16 & 7);
            a[kk] = *(const bf16x8*)&arow[gr << 3];
        }
    }

    for (int t = t0; t <= t1; ++t) {
        f32x4 acc[8];
        #pragma unroll
        for (int nt = 0; nt < 8; ++nt) acc[nt] = (f32x4){0.f, 0.f, 0.f, 0.f};

        // B fragments: contiguous wave loads, L1/L2-hot (32 KB per type)
        const __bf16* wt = wbf + ((size_t)t * 32) * 512;   // t*8*4*64*8
        #pragma unroll
        for (int nt = 0; nt < 8; ++nt) {
            #pragma unroll
            for (int kk = 0; kk < 4; ++kk) {
                bf16x8 b = *(const bf16x8*)&wt[(((nt << 2) | kk) << 9) + (lane << 3)];
                acc[nt] = __builtin_amdgcn_mfma_f32_16x16x32_bf16(a[kk], b, acc[nt], 0, 0, 0);
            }
        }

        // ---- Epilogue: D[row=q*4+reg][col=nt*16+n16]; lane-contiguous stores ----
        const int rbase = row0 + wave * 16 + q * 4;
        bool m0 = true, m1 = true, m2 = true, m3 = true;
        if (!uniform) {
            m0 = (tv[rbase + 0] == t);
            m1 = (tv[rbase + 1] == t);
            m2 = (tv[rbase + 2] == t);
            m3 = (tv[rbase + 3] == t);
        }
        #pragma unroll
        for (int nt = 0; nt < 8; ++nt) {
            int   col = nt * 16 + n16;
            float bv  = bias[t * DD + col];
            float* o  = out + (size_t)rbase * DD + col;
            if (m0) o[0 * DD] = acc[nt][0] + bv;
            if (m1) o[1 * DD] = acc[nt][1] + bv;
            if (m2) o[2 * DD] = acc[nt][2] + bv;
            if (m3) o[3 * DD] = acc[nt][3] + bv;
        }
    }
}

extern "C" void kernel_launch(void* const* d_in, const int* in_sizes, int n_in,
                              void* d_out, int out_size, void* d_ws, size_t ws_size,
                              hipStream_t stream) {
    const float* x    = (const float*)d_in[0];
    const int*   tv   = (const int*)d_in[1];
    const float* w    = (const float*)d_in[2];
    const float* bias = (const float*)d_in[3];
    float*       out  = (float*)d_out;
    unsigned short* wbf = (unsigned short*)d_ws;   // 16*128*128*2 = 512 KB

    int nrows = in_sizes[0] / DD;                  // 131072
    int grid  = nrows / BM;                        // 2048

    hipLaunchKernelGGL(transpose_w_frag_kernel, dim3(T_TYPES * 4), dim3(256), 0, stream,
                       w, wbf);
    hipLaunchKernelGGL(hetero_main_kernel, dim3(grid), dim3(256), 0, stream,
                       x, tv, (const __bf16*)wbf, bias, out);
}